// Round 11
// baseline (244.632 us; speedup 1.0000x reference)
//
#include <hip/hip_runtime.h>
#include <math.h>

// Problem constants
#define B_  8
#define S_  384
#define H_  12
#define HD_ 64
#define E_  768
#define D_  768

typedef float  floatx4 __attribute__((ext_vector_type(4)));
typedef __bf16 bf16x8  __attribute__((ext_vector_type(8)));
typedef unsigned int ux4 __attribute__((ext_vector_type(4)));

__device__ __forceinline__ unsigned short f2bf(float f) {
    union { float f; unsigned u; } x; x.f = f;
    unsigned r = x.u + 0x7fff + ((x.u >> 16) & 1);
    return (unsigned short)(r >> 16);
}
__device__ __forceinline__ float bf2f(unsigned short u) {
    union { unsigned u; float f; } x; x.u = ((unsigned)u) << 16;
    return x.f;
}
__device__ __forceinline__ bf16x8 gld8(const unsigned short* p) {
    return __builtin_bit_cast(bf16x8, *(const ux4*)p);
}
// swizzled chunk address (shorts) for 128B-row tiles staged via global_load_lds
__device__ __forceinline__ int tadr(int row, int cD) {
    return (row * 8 + (cD ^ (row & 7))) * 8;
}
__device__ __forceinline__ bf16x8 lds8(const unsigned short* base, int row, int cD) {
    return __builtin_bit_cast(bf16x8, *(const ux4*)(base + tadr(row, cD)));
}

// ---------------------------------------------------------------------------
// Fused fp32 -> bf16 convert. grid=(576,11).
// ---------------------------------------------------------------------------
__global__ __launch_bounds__(256) void convert_all(
    const float* __restrict__ x,
    const float* __restrict__ Wq, const float* __restrict__ Wk,
    const float* __restrict__ Wv, const float* __restrict__ Wo,
    const float* __restrict__ Wpk, const float* __restrict__ Wpq,
    const float* __restrict__ rel128,
    unsigned short* __restrict__ xb,
    unsigned short* __restrict__ wqb, unsigned short* __restrict__ wkb,
    unsigned short* __restrict__ wvb, unsigned short* __restrict__ wob,
    unsigned short* __restrict__ wpkb, unsigned short* __restrict__ wpqb,
    unsigned short* __restrict__ relb)
{
    const int seg = blockIdx.y;
    const int e = (blockIdx.x * 256 + threadIdx.x) * 4;
    const float* src;
    unsigned short* dst;
    if (seg < 4)       { src = x + (size_t)seg * 589824; dst = xb + (size_t)seg * 589824; }
    else if (seg == 4) { src = Wq;  dst = wqb; }
    else if (seg == 5) { src = Wk;  dst = wkb; }
    else if (seg == 6) { src = Wv;  dst = wvb; }
    else if (seg == 7) { src = Wo;  dst = wob; }
    else if (seg == 8) { src = Wpk; dst = wpkb; }
    else if (seg == 9) { src = Wpq; dst = wpqb; }
    else               { src = rel128; dst = relb; }

    float4 v;
    if (seg == 10 && e >= 767 * 768) v = make_float4(0.f, 0.f, 0.f, 0.f);
    else                             v = *(const float4*)(src + e);
    ushort4 o;
    o.x = f2bf(v.x); o.y = f2bf(v.y); o.z = f2bf(v.z); o.w = f2bf(v.w);
    *(ushort4*)(dst + e) = o;
}

// ---------------------------------------------------------------------------
// Fused projection GEMMs (Q,K,Vt,pk,pq) in one launch. grid=(6,24,5).
// ---------------------------------------------------------------------------
__global__ __launch_bounds__(256) void proj_all(
    const unsigned short* __restrict__ xb, const unsigned short* __restrict__ relb,
    const unsigned short* __restrict__ wq, const unsigned short* __restrict__ wk,
    const unsigned short* __restrict__ wv, const unsigned short* __restrict__ wpk,
    const unsigned short* __restrict__ wpq,
    const float* __restrict__ bq, const float* __restrict__ bk,
    const float* __restrict__ bv, const float* __restrict__ bpk,
    const float* __restrict__ bpq,
    unsigned short* __restrict__ qb, unsigned short* __restrict__ kb,
    unsigned short* __restrict__ vtb, unsigned short* __restrict__ pkb,
    unsigned short* __restrict__ pqb)
{
    const int z = blockIdx.z;
    if (z >= 3 && blockIdx.y >= 6) return;

    const unsigned short* A = (z < 3) ? xb : relb;
    const unsigned short* W = (z == 0) ? wq : (z == 1) ? wk : (z == 2) ? wv
                            : (z == 3) ? wpk : wpq;
    const float* bias = (z == 0) ? bq : (z == 1) ? bk : (z == 2) ? bv
                      : (z == 3) ? bpk : bpq;
    unsigned short* C = (z == 0) ? qb : (z == 1) ? kb : (z == 2) ? vtb
                      : (z == 3) ? pkb : pqb;

    __shared__ unsigned short As[128 * 32];
    __shared__ unsigned short Ws[128 * 32];

    const int tid  = threadIdx.x;
    const int lane = tid & 63;
    const int wv_  = tid >> 6;
    const int wy   = wv_ >> 1, wx = wv_ & 1;
    const int quad = lane >> 4, l16 = lane & 15;
    const int m0 = blockIdx.y * 128, n0 = blockIdx.x * 128;

    floatx4 acc[4][4];
#pragma unroll
    for (int i = 0; i < 4; ++i)
#pragma unroll
        for (int j = 0; j < 4; ++j) acc[i][j] = (floatx4){0.f, 0.f, 0.f, 0.f};

    const int koff = quad * 8;

    for (int k0 = 0; k0 < 768; k0 += 32) {
        __syncthreads();
#pragma unroll
        for (int r = 0; r < 2; ++r) {
            int idx = tid + 256 * r;
            int row = idx >> 2, c8 = (idx & 3) * 8;
            const unsigned short* ga = A + (size_t)(m0 + row) * 768 + k0 + c8;
            const unsigned short* gw = W + (size_t)(n0 + row) * 768 + k0 + c8;
            __builtin_amdgcn_global_load_lds(
                (__attribute__((address_space(1))) void*)ga,
                (__attribute__((address_space(3))) void*)&As[idx * 8], 16, 0, 0);
            __builtin_amdgcn_global_load_lds(
                (__attribute__((address_space(1))) void*)gw,
                (__attribute__((address_space(3))) void*)&Ws[idx * 8], 16, 0, 0);
        }
        __syncthreads();

        bf16x8 a[4], b[4];
#pragma unroll
        for (int mi = 0; mi < 4; ++mi)
            a[mi] = __builtin_bit_cast(bf16x8,
                *(const ux4*)&As[(wy * 64 + mi * 16 + l16) * 32 + koff]);
#pragma unroll
        for (int ni = 0; ni < 4; ++ni)
            b[ni] = __builtin_bit_cast(bf16x8,
                *(const ux4*)&Ws[(wx * 64 + ni * 16 + l16) * 32 + koff]);
#pragma unroll
        for (int mi = 0; mi < 4; ++mi)
#pragma unroll
            for (int ni = 0; ni < 4; ++ni)
                acc[mi][ni] = __builtin_amdgcn_mfma_f32_16x16x32_bf16(
                    a[mi], b[ni], acc[mi][ni], 0, 0, 0);
    }

#pragma unroll
    for (int ni = 0; ni < 4; ++ni) {
        const int n = n0 + wx * 64 + ni * 16 + l16;
        const float bn = bias[n];
#pragma unroll
        for (int mi = 0; mi < 4; ++mi) {
            const int mbase = m0 + wy * 64 + mi * 16 + quad * 4;
            if (z == 2) {
                const int bb = mbase / S_, s = mbase - bb * S_;
                const int h = n >> 6, hd = n & 63;
                ushort4 o;
                o.x = f2bf(acc[mi][ni][0] + bn);
                o.y = f2bf(acc[mi][ni][1] + bn);
                o.z = f2bf(acc[mi][ni][2] + bn);
                o.w = f2bf(acc[mi][ni][3] + bn);
                *(ushort4*)&C[(((size_t)(bb * H_ + h) << 6) + hd) * S_ + s] = o;
            } else if (z < 2) {
#pragma unroll
                for (int reg = 0; reg < 4; ++reg) {
                    const int m = mbase + reg;
                    const int bb = m / S_, s = m - bb * S_;
                    const int h = n >> 6, hd = n & 63;
                    C[(((size_t)(bb * H_ + h) * S_ + s) << 6) + hd] =
                        f2bf(acc[mi][ni][reg] + bn);
                }
            } else {
#pragma unroll
                for (int reg = 0; reg < 4; ++reg)
                    C[(size_t)(mbase + reg) * 768 + n] = f2bf(acc[mi][ni][reg] + bn);
            }
        }
    }
}

// ---------------------------------------------------------------------------
// Output projection: fp32 out = valsb(bf16) @ Wo^T(bf16) + bo. grid=(6,24).
// ---------------------------------------------------------------------------
__global__ __launch_bounds__(256) void gemm_out(
    const unsigned short* __restrict__ A, const unsigned short* __restrict__ W,
    const float* __restrict__ bias, float* __restrict__ C)
{
    __shared__ unsigned short As[128 * 32];
    __shared__ unsigned short Ws[128 * 32];

    const int tid  = threadIdx.x;
    const int lane = tid & 63;
    const int wv_  = tid >> 6;
    const int wy   = wv_ >> 1, wx = wv_ & 1;
    const int quad = lane >> 4, l16 = lane & 15;
    const int m0 = blockIdx.y * 128, n0 = blockIdx.x * 128;

    floatx4 acc[4][4];
#pragma unroll
    for (int i = 0; i < 4; ++i)
#pragma unroll
        for (int j = 0; j < 4; ++j) acc[i][j] = (floatx4){0.f, 0.f, 0.f, 0.f};

    const int koff = quad * 8;

    for (int k0 = 0; k0 < 768; k0 += 32) {
        __syncthreads();
#pragma unroll
        for (int r = 0; r < 2; ++r) {
            int idx = tid + 256 * r;
            int row = idx >> 2, c8 = (idx & 3) * 8;
            const unsigned short* ga = A + (size_t)(m0 + row) * 768 + k0 + c8;
            const unsigned short* gw = W + (size_t)(n0 + row) * 768 + k0 + c8;
            __builtin_amdgcn_global_load_lds(
                (__attribute__((address_space(1))) void*)ga,
                (__attribute__((address_space(3))) void*)&As[idx * 8], 16, 0, 0);
            __builtin_amdgcn_global_load_lds(
                (__attribute__((address_space(1))) void*)gw,
                (__attribute__((address_space(3))) void*)&Ws[idx * 8], 16, 0, 0);
        }
        __syncthreads();

        bf16x8 a[4], b[4];
#pragma unroll
        for (int mi = 0; mi < 4; ++mi)
            a[mi] = __builtin_bit_cast(bf16x8,
                *(const ux4*)&As[(wy * 64 + mi * 16 + l16) * 32 + koff]);
#pragma unroll
        for (int ni = 0; ni < 4; ++ni)
            b[ni] = __builtin_bit_cast(bf16x8,
                *(const ux4*)&Ws[(wx * 64 + ni * 16 + l16) * 32 + koff]);
#pragma unroll
        for (int mi = 0; mi < 4; ++mi)
#pragma unroll
            for (int ni = 0; ni < 4; ++ni)
                acc[mi][ni] = __builtin_amdgcn_mfma_f32_16x16x32_bf16(
                    a[mi], b[ni], acc[mi][ni], 0, 0, 0);
    }

#pragma unroll
    for (int ni = 0; ni < 4; ++ni) {
        const int n = n0 + wx * 64 + ni * 16 + l16;
        const float bn = bias[n];
#pragma unroll
        for (int mi = 0; mi < 4; ++mi)
#pragma unroll
            for (int reg = 0; reg < 4; ++reg) {
                const int m = m0 + wy * 64 + mi * 16 + quad * 4 + reg;
                C[(size_t)m * 768 + n] = acc[mi][ni][reg] + bn;
            }
    }
}

// ---------------------------------------------------------------------------
// MFMA flash attention v9 — plain-store score tiles (NO LDS read-modify-write).
// Key fact: dd = ii-jj+63 is a bijection per cell, so c2p and p2c each write
// every (ii,jj) exactly ONCE -> plain stores into separate banded bf16
// buffers; softmax sums CP + C2Ps + P2Cs on read (pipelined loads, no alias
// serialization). K and Vt fragments are hoisted register gathers (one
// latency window); PK/PQ stay LDS-staged via global_load_lds (R10 win).
// LDS = PKs 16K + PQs 16K + CP 17K + C2Ps 9K + P2Cs 9K = 67 KB -> 2 blk/CU.
// grid = (6 it, 12 h, 48 = b*6+jt); 256 thr = 4 waves; wave w owns rows
// [16w,16w+16). Zero __syncthreads after the staging barrier.
// ---------------------------------------------------------------------------
__global__ __launch_bounds__(256) void attn_mfma(
    const unsigned short* __restrict__ qg, const unsigned short* __restrict__ kg,
    const unsigned short* __restrict__ vtg,
    const unsigned short* __restrict__ pkg, const unsigned short* __restrict__ pqg,
    const int* __restrict__ seg, const float* __restrict__ sep,
    const int* __restrict__ mask,
    const float* __restrict__ same_bias, const float* __restrict__ cross_bias,
    const float* __restrict__ sep_scale, const float* __restrict__ sep_decay,
    unsigned short* __restrict__ part_O, float* __restrict__ part_ml)
{
    __shared__ unsigned short PKs[128 * 64];   // 16 KB [ddloc][d], swizzled chunks
    __shared__ unsigned short PQs[128 * 64];   // 16 KB
    __shared__ float CP[64 * 68];              // 17 KB c2c tile; P aliased later
    __shared__ unsigned short C2Ps[64 * 72];   //  9 KB c2p tile (bf16)
    __shared__ unsigned short P2Cs[64 * 72];   //  9 KB p2c tile (bf16)

    const int tid  = threadIdx.x;
    const int lane = tid & 63, w = tid >> 6;
    const int l16  = lane & 15, quad = lane >> 4;
    const int ty = tid >> 4, tx = tid & 15;
    const int it = blockIdx.x, h = blockIdx.y;
    const int b  = blockIdx.z / 6, jt = blockIdx.z - 6 * b;
    const int i0 = it * 64, j0 = jt * 64;
    const size_t bh = (size_t)(b * H_ + h);

    const unsigned short* kbase  = kg  + bh * S_ * 64;
    const unsigned short* vtbase = vtg + bh * 64 * S_;
    const int dbase = i0 - j0 + 320;           // pk/pq window base (0..640)

    // ---- stage PK + PQ (128 rows x 8 chunks each) ----
#pragma unroll
    for (int r = 0; r < 4; ++r) {
        const int idx = tid + 256 * r;              // 0..1023
        const int row = idx >> 3, cL = idx & 7;
        const int cD = cL ^ (row & 7);
        const size_t go = (size_t)(dbase + row) * 768 + h * 64 + cD * 8;
        __builtin_amdgcn_global_load_lds(
            (__attribute__((address_space(1))) void*)(pkg + go),
            (__attribute__((address_space(3))) void*)&PKs[idx * 8], 16, 0, 0);
        __builtin_amdgcn_global_load_lds(
            (__attribute__((address_space(1))) void*)(pqg + go),
            (__attribute__((address_space(3))) void*)&PQs[idx * 8], 16, 0, 0);
    }

    // ---- hoisted register gathers: Q, K, Vt (one latency window) ----
    bf16x8 qf[2];
#pragma unroll
    for (int ks = 0; ks < 2; ++ks)
        qf[ks] = gld8(qg + (bh * S_ + i0 + 16 * w + l16) * 64 + ks * 32 + quad * 8);

    bf16x8 kf[4][2];
#pragma unroll
    for (int nj = 0; nj < 4; ++nj)
#pragma unroll
        for (int ks = 0; ks < 2; ++ks)
            kf[nj][ks] = gld8(kbase + (size_t)(j0 + 16 * nj + l16) * 64 + ks * 32 + quad * 8);

    bf16x8 vtf[4][2];
#pragma unroll
    for (int nd = 0; nd < 4; ++nd)
#pragma unroll
        for (int ks = 0; ks < 2; ++ks)
            vtf[nd][ks] = gld8(vtbase + (size_t)(16 * nd + l16) * S_ + j0 + ks * 32 + quad * 8);

    // i-side metadata
    float ai_r[4]; int si_r[4];
#pragma unroll
    for (int p = 0; p < 4; ++p) {
        const int ii = 4 * ty + p;
        ai_r[p] = fabsf(sep[b * S_ + i0 + ii]);
        si_r[p] = seg[b * S_ + i0 + ii];
    }

    const float sb  = same_bias[h];
    const float cb  = cross_bias[h];
    const float ssc = sep_scale[h];
    const float sd  = sep_decay[h];
    const float dec = fmaxf(sd, 0.f) + log1pf(__expf(-fabsf(sd))) + 1e-4f;
    const float isc = 0.07216878364870323f;    // 1/sqrt(64*3)

    __syncthreads();   // the ONE barrier: PK/PQ staging complete

    // ---- c2c: CP rows strip w = q . k (plain stores) ----
#pragma unroll
    for (int nj = 0; nj < 4; ++nj) {
        floatx4 acc = (floatx4){0.f, 0.f, 0.f, 0.f};
#pragma unroll
        for (int ks = 0; ks < 2; ++ks)
            acc = __builtin_amdgcn_mfma_f32_16x16x32_bf16(qf[ks], kf[nj][ks], acc, 0, 0, 0);
#pragma unroll
        for (int reg = 0; reg < 4; ++reg) {
            const int ii = 16 * w + quad * 4 + reg;
            CP[ii * 68 + 16 * nj + l16] = acc[reg];
        }
    }

    // ---- c2p: frags nd = w..w+4; PLAIN bf16 store at jj = ii-ddloc+63 ----
#pragma unroll
    for (int f = 0; f < 5; ++f) {
        const int nd = w + f;
        floatx4 acc = (floatx4){0.f, 0.f, 0.f, 0.f};
#pragma unroll
        for (int ks = 0; ks < 2; ++ks) {
            bf16x8 bf = lds8(PKs, 16 * nd + l16, ks * 4 + quad);
            acc = __builtin_amdgcn_mfma_f32_16x16x32_bf16(qf[ks], bf, acc, 0, 0, 0);
        }
        const int ddloc = 16 * nd + l16;
#pragma unroll
        for (int reg = 0; reg < 4; ++reg) {
            const int ii = 16 * w + quad * 4 + reg;
            const int jj = ii - ddloc + 63;
            if (jj >= 0 && jj < 64)
                C2Ps[ii * 72 + jj] = f2bf(acc[reg]);   // bijective: one writer
        }
    }

    // ---- p2c: A=PQ (m=ddloc), B=K (n=jj); frags nd+nj in {w+3,w+4};
    //      PLAIN bf16 store, guard ii in strip w ----
#pragma unroll
    for (int f = 0; f < 5; ++f) {
        const int nd = w + f;
        bf16x8 pqf[2];
#pragma unroll
        for (int ks = 0; ks < 2; ++ks)
            pqf[ks] = lds8(PQs, 16 * nd + l16, ks * 4 + quad);
#pragma unroll
        for (int g = 0; g < 2; ++g) {
            const int nj = (g == 0) ? (3 - f) : (4 - f);
            if (nj < 0 || nj > 3) continue;
            floatx4 acc = (floatx4){0.f, 0.f, 0.f, 0.f};
#pragma unroll
            for (int ks = 0; ks < 2; ++ks)
                acc = __builtin_amdgcn_mfma_f32_16x16x32_bf16(pqf[ks], kf[nj][ks], acc, 0, 0, 0);
            const int jj = 16 * nj + l16;
#pragma unroll
            for (int reg = 0; reg < 4; ++reg) {
                const int ddloc = 16 * nd + quad * 4 + reg;
                const int ii = ddloc + jj - 63;
                if (ii >= 16 * w && ii < 16 * w + 16)
                    P2Cs[ii * 72 + jj] = f2bf(acc[reg]);  // bijective: one writer
            }
        }
    }

    // ---- softmax (rows strip w): sum 3 tiles on read; no prior-write alias ----
    unsigned short* Pp = (unsigned short*)CP;      // P aliased, pitch 136 shorts
    float* pml = part_ml + (size_t)(jt * 576 + ((b * H_ + h) * 6 + it)) * 128;
#pragma unroll
    for (int p = 0; p < 4; ++p) {
        const int ii = 4 * ty + p;
        const float aii = ai_r[p];
        const int   sii = si_r[p];
        const float4 cc = *(const float4*)&CP[ii * 68 + 4 * tx];
        const ushort4 u1 = *(const ushort4*)&C2Ps[ii * 72 + 4 * tx];
        const ushort4 u2 = *(const ushort4*)&P2Cs[ii * 72 + 4 * tx];
        float lg[4];
        lg[0] = cc.x + bf2f(u1.x) + bf2f(u2.x);
        lg[1] = cc.y + bf2f(u1.y) + bf2f(u2.y);
        lg[2] = cc.z + bf2f(u1.z) + bf2f(u2.z);
        lg[3] = cc.w + bf2f(u1.w) + bf2f(u2.w);
        float tmax = -INFINITY;
#pragma unroll
        for (int r = 0; r < 4; ++r) {
            const int jl = 4 * tx + r;
            float xv = lg[r] * isc;
            const float ajv = fabsf(sep[b * S_ + j0 + jl]);
            const int   sjv = seg[b * S_ + j0 + jl];
            const float gap = fabsf(aii - ajv);
            const float bias = (sii == sjv) ? sb
                             : cb + __expf(-gap * dec) * ssc;
            xv += bias;
            if (mask[b * S_ + j0 + jl] == 0) xv = -9.0e15f;
            lg[r] = xv;
            tmax = fmaxf(tmax, xv);
        }
#pragma unroll
        for (int off = 1; off < 16; off <<= 1)
            tmax = fmaxf(tmax, __shfl_xor(tmax, off));
        float rs = 0.f;
        ushort4 pw;
#pragma unroll
        for (int r = 0; r < 4; ++r) {
            const float e = __expf(lg[r] - tmax);
            rs += e;
            ((unsigned short*)&pw)[r] = f2bf(e);
        }
#pragma unroll
        for (int off = 1; off < 16; off <<= 1)
            rs += __shfl_xor(rs, off);
        if (tx == 0) {
            pml[ii]      = tmax;
            pml[64 + ii] = rs;
        }
        // write AFTER this wave's reads of CP row ii (same-wave program order)
        *(ushort4*)&Pp[ii * 136 + 4 * tx] = pw;
    }

    // ---- PV (rows strip w): O = P x Vt (Vt from registers) ----
    bf16x8 pA[2];
#pragma unroll
    for (int ks = 0; ks < 2; ++ks)
        pA[ks] = __builtin_bit_cast(bf16x8,
            *(const ux4*)&Pp[(16 * w + l16) * 136 + ks * 32 + quad * 8]);
    floatx4 O[4];
#pragma unroll
    for (int nd = 0; nd < 4; ++nd) {
        O[nd] = (floatx4){0.f, 0.f, 0.f, 0.f};
#pragma unroll
        for (int ks = 0; ks < 2; ++ks)
            O[nd] = __builtin_amdgcn_mfma_f32_16x16x32_bf16(pA[ks], vtf[nd][ks], O[nd], 0, 0, 0);
    }

    // ---- epilogue: write unnormalized partial O ----
    unsigned short* pO = part_O + (size_t)(jt * 576 + ((b * H_ + h) * 6 + it)) * 4096;
#pragma unroll
    for (int nd = 0; nd < 4; ++nd) {
        const int d = 16 * nd + l16;
#pragma unroll
        for (int reg = 0; reg < 4; ++reg) {
            const int ii = 16 * w + quad * 4 + reg;
            pO[ii * 64 + d] = f2bf(O[nd][reg]);
        }
    }
}

// ---------------------------------------------------------------------------
// Merge the 6 split-j partials -> vals (bf16, (B,S,E)). grid=576, 256 thr.
// ---------------------------------------------------------------------------
__global__ __launch_bounds__(256) void merge_attn(
    const unsigned short* __restrict__ part_O, const float* __restrict__ part_ml,
    unsigned short* __restrict__ vals)
{
    const int idx = blockIdx.x;                 // ((b*H+h)*6+it)
    const int b  = idx / (H_ * 6);
    const int r  = idx - b * H_ * 6;
    const int h  = r / 6, it = r - h * 6;
    const int tid = threadIdx.x;
    const int ii = tid >> 2, c = (tid & 3) * 16;

    float m[6], l[6];
#pragma unroll
    for (int jc = 0; jc < 6; ++jc) {
        const float* pml = part_ml + (size_t)(jc * 576 + idx) * 128;
        m[jc] = pml[ii];
        l[jc] = pml[64 + ii];
    }
    float M = m[0];
#pragma unroll
    for (int jc = 1; jc < 6; ++jc) M = fmaxf(M, m[jc]);
    float wsum = 0.f, wc[6];
#pragma unroll
    for (int jc = 0; jc < 6; ++jc) {
        wc[jc] = __expf(m[jc] - M);
        wsum += wc[jc] * l[jc];
    }
    const float inv = (wsum > 0.f) ? 1.f / wsum : 0.f;

    float o[16];
#pragma unroll
    for (int e = 0; e < 16; ++e) o[e] = 0.f;
#pragma unroll
    for (int jc = 0; jc < 6; ++jc) {
        const unsigned short* pO = part_O + ((size_t)(jc * 576 + idx)) * 4096
                                 + ii * 64 + c;
        ux4 u0 = *(const ux4*)pO;
        ux4 u1 = *(const ux4*)(pO + 8);
        const unsigned short* us0 = (const unsigned short*)&u0;
        const unsigned short* us1 = (const unsigned short*)&u1;
#pragma unroll
        for (int e = 0; e < 8; ++e) {
            o[e]     += wc[jc] * bf2f(us0[e]);
            o[8 + e] += wc[jc] * bf2f(us1[e]);
        }
    }
    ushort4 w0, w1, w2, w3;
#pragma unroll
    for (int e = 0; e < 4; ++e) {
        ((unsigned short*)&w0)[e] = f2bf(o[e] * inv);
        ((unsigned short*)&w1)[e] = f2bf(o[4 + e] * inv);
        ((unsigned short*)&w2)[e] = f2bf(o[8 + e] * inv);
        ((unsigned short*)&w3)[e] = f2bf(o[12 + e] * inv);
    }
    unsigned short* dst = vals + ((size_t)(b * S_ + it * 64 + ii)) * E_ + h * 64 + c;
    *(ushort4*)(dst)      = w0;
    *(ushort4*)(dst + 4)  = w1;
    *(ushort4*)(dst + 8)  = w2;
    *(ushort4*)(dst + 12) = w3;
}

// ---------------------------------------------------------------------------
// Launcher. Workspace (shorts unless noted): xb 2359296; 7x589824 weights/rel;
// qb,kb,vtb 3x2359296; pkb,pqb 2x589824; valsb 2359296; part_O 6x576x4096;
// part_ml fp32 6x576x128. ~69 MiB.
// ---------------------------------------------------------------------------
extern "C" void kernel_launch(void* const* d_in, const int* in_sizes, int n_in,
                              void* d_out, int out_size, void* d_ws, size_t ws_size,
                              hipStream_t stream)
{
    const float* x         = (const float*)d_in[0];
    const int*   mask      = (const int*)d_in[1];
    const int*   seg       = (const int*)d_in[2];
    const float* sep       = (const float*)d_in[3];
    const float* Wq        = (const float*)d_in[4];
    const float* bq        = (const float*)d_in[5];
    const float* Wk        = (const float*)d_in[6];
    const float* bk        = (const float*)d_in[7];
    const float* Wv        = (const float*)d_in[8];
    const float* bv        = (const float*)d_in[9];
    const float* rel_emb   = (const float*)d_in[10];
    const float* Wpk       = (const float*)d_in[11];
    const float* bpk       = (const float*)d_in[12];
    const float* Wpq       = (const float*)d_in[13];
    const float* bpq       = (const float*)d_in[14];
    const float* same_bias = (const float*)d_in[15];
    const float* cross_bias= (const float*)d_in[16];
    const float* sep_scale = (const float*)d_in[17];
    const float* sep_decay = (const float*)d_in[18];
    const float* Wo        = (const float*)d_in[19];
    const float* bo        = (const float*)d_in[20];

    const size_t QKVN = (size_t)B_ * S_ * E_;   // 2359296
    const size_t WN   = (size_t)768 * 768;      //  589824

    unsigned short* xb    = (unsigned short*)d_ws;
    unsigned short* wqb   = xb   + QKVN;
    unsigned short* wkb   = wqb  + WN;
    unsigned short* wvb   = wkb  + WN;
    unsigned short* wob   = wvb  + WN;
    unsigned short* wpkb  = wob  + WN;
    unsigned short* wpqb  = wpkb + WN;
    unsigned short* relb  = wpqb + WN;
    unsigned short* qb    = relb + WN;
    unsigned short* kb    = qb   + QKVN;
    unsigned short* vtb   = kb   + QKVN;
    unsigned short* pkb   = vtb  + QKVN;
    unsigned short* pqb   = pkb  + WN;
    unsigned short* valsb = pqb  + WN;
    unsigned short* partO = valsb + QKVN;                       // 6*576*4096 shorts
    float*          partml= (float*)(partO + (size_t)6 * 576 * 4096);

    // 1) convert all operands to bf16
    convert_all<<<dim3(576, 11), 256, 0, stream>>>(
        x, Wq, Wk, Wv, Wo, Wpk, Wpq, rel_emb + (size_t)128 * D_,
        xb, wqb, wkb, wvb, wob, wpkb, wpqb, relb);

    // 2) fused Q/K/Vt/pk/pq projections
    proj_all<<<dim3(6, 24, 5), 256, 0, stream>>>(
        xb, relb, wqb, wkb, wvb, wpkb, wpqb,
        bq, bk, bv, bpk, bpq, qb, kb, vtb, pkb, pqb);

    // 3) MFMA flash attention, plain-store score tiles, split-j x6
    attn_mfma<<<dim3(6, 12, 48), 256, 0, stream>>>(
        qb, kb, vtb, pkb, pqb, seg, sep, mask,
        same_bias, cross_bias, sep_scale, sep_decay, partO, partml);

    // 4) merge partials -> valsb
    merge_attn<<<dim3(576), 256, 0, stream>>>(partO, partml, valsb);

    // 5) output projection
    gemm_out<<<dim3(6, 24), 256, 0, stream>>>(valsb, wob, bo, (float*)d_out);
}

// Round 12
// 212.602 us; speedup vs baseline: 1.1507x; 1.1507x over previous
//
#include <hip/hip_runtime.h>
#include <math.h>

// Problem constants
#define B_  8
#define S_  384
#define H_  12
#define HD_ 64
#define E_  768
#define D_  768

typedef float  floatx4 __attribute__((ext_vector_type(4)));
typedef __bf16 bf16x8  __attribute__((ext_vector_type(8)));
typedef unsigned int ux4 __attribute__((ext_vector_type(4)));

__device__ __forceinline__ unsigned short f2bf(float f) {
    union { float f; unsigned u; } x; x.f = f;
    unsigned r = x.u + 0x7fff + ((x.u >> 16) & 1);
    return (unsigned short)(r >> 16);
}
__device__ __forceinline__ float bf2f(unsigned short u) {
    union { unsigned u; float f; } x; x.u = ((unsigned)u) << 16;
    return x.f;
}
__device__ __forceinline__ bf16x8 gld8(const unsigned short* p) {
    return __builtin_bit_cast(bf16x8, *(const ux4*)p);
}
// swizzled chunk address (shorts) for 128B-row tiles staged via global_load_lds
__device__ __forceinline__ int tadr(int row, int cD) {
    return (row * 8 + (cD ^ (row & 7))) * 8;
}
__device__ __forceinline__ bf16x8 lds8(const unsigned short* base, int row, int cD) {
    return __builtin_bit_cast(bf16x8, *(const ux4*)(base + tadr(row, cD)));
}

// ---------------------------------------------------------------------------
// Fused fp32 -> bf16 convert. grid=(576,11).
// ---------------------------------------------------------------------------
__global__ __launch_bounds__(256) void convert_all(
    const float* __restrict__ x,
    const float* __restrict__ Wq, const float* __restrict__ Wk,
    const float* __restrict__ Wv, const float* __restrict__ Wo,
    const float* __restrict__ Wpk, const float* __restrict__ Wpq,
    const float* __restrict__ rel128,
    unsigned short* __restrict__ xb,
    unsigned short* __restrict__ wqb, unsigned short* __restrict__ wkb,
    unsigned short* __restrict__ wvb, unsigned short* __restrict__ wob,
    unsigned short* __restrict__ wpkb, unsigned short* __restrict__ wpqb,
    unsigned short* __restrict__ relb)
{
    const int seg = blockIdx.y;
    const int e = (blockIdx.x * 256 + threadIdx.x) * 4;
    const float* src;
    unsigned short* dst;
    if (seg < 4)       { src = x + (size_t)seg * 589824; dst = xb + (size_t)seg * 589824; }
    else if (seg == 4) { src = Wq;  dst = wqb; }
    else if (seg == 5) { src = Wk;  dst = wkb; }
    else if (seg == 6) { src = Wv;  dst = wvb; }
    else if (seg == 7) { src = Wo;  dst = wob; }
    else if (seg == 8) { src = Wpk; dst = wpkb; }
    else if (seg == 9) { src = Wpq; dst = wpqb; }
    else               { src = rel128; dst = relb; }

    float4 v;
    if (seg == 10 && e >= 767 * 768) v = make_float4(0.f, 0.f, 0.f, 0.f);
    else                             v = *(const float4*)(src + e);
    ushort4 o;
    o.x = f2bf(v.x); o.y = f2bf(v.y); o.z = f2bf(v.z); o.w = f2bf(v.w);
    *(ushort4*)(dst + e) = o;
}

// ---------------------------------------------------------------------------
// Projection GEMMs (Q,K,Vt,pk,pq), 64x128 tile, BK=64, flat grid of 1008:
//   bid <  864 : z = bid/288 (Q,K,Vt), 48 m-tiles x 6 n-tiles
//   bid >= 864 : z = 3 + (bid-864)/72 (pk,pq), 12 m-tiles x 6 n-tiles
// 4 waves = 4 N-strips of 32; 12 k-steps (half the barrier drains of BK=32);
// LDS 24 KB (As 8K + Ws 16K) -> high residency; chunk-XOR swizzled staging.
// ---------------------------------------------------------------------------
__global__ __launch_bounds__(256) void proj_all(
    const unsigned short* __restrict__ xb, const unsigned short* __restrict__ relb,
    const unsigned short* __restrict__ wq, const unsigned short* __restrict__ wk,
    const unsigned short* __restrict__ wv, const unsigned short* __restrict__ wpk,
    const unsigned short* __restrict__ wpq,
    const float* __restrict__ bq, const float* __restrict__ bk,
    const float* __restrict__ bv, const float* __restrict__ bpk,
    const float* __restrict__ bpq,
    unsigned short* __restrict__ qb, unsigned short* __restrict__ kb,
    unsigned short* __restrict__ vtb, unsigned short* __restrict__ pkb,
    unsigned short* __restrict__ pqb)
{
    const int bid = blockIdx.x;
    int z, mt, nt;
    if (bid < 864) {
        z = bid / 288; const int r = bid - z * 288; mt = r / 6; nt = r - mt * 6;
    } else {
        const int r2 = bid - 864; z = 3 + r2 / 72;
        const int r = r2 % 72; mt = r / 6; nt = r - mt * 6;
    }
    const int m0 = mt * 64, n0 = nt * 128;

    const unsigned short* A = (z < 3) ? xb : relb;
    const unsigned short* W = (z == 0) ? wq : (z == 1) ? wk : (z == 2) ? wv
                            : (z == 3) ? wpk : wpq;
    const float* bias = (z == 0) ? bq : (z == 1) ? bk : (z == 2) ? bv
                      : (z == 3) ? bpk : bpq;
    unsigned short* C = (z == 0) ? qb : (z == 1) ? kb : (z == 2) ? vtb
                      : (z == 3) ? pkb : pqb;

    __shared__ unsigned short As[64 * 64];     //  8 KB
    __shared__ unsigned short Ws[128 * 64];    // 16 KB

    const int tid  = threadIdx.x;
    const int lane = tid & 63;
    const int wv_  = tid >> 6;                 // N-strip of 32
    const int quad = lane >> 4, l16 = lane & 15;

    floatx4 acc[4][2];
#pragma unroll
    for (int i = 0; i < 4; ++i)
#pragma unroll
        for (int j = 0; j < 2; ++j) acc[i][j] = (floatx4){0.f, 0.f, 0.f, 0.f};

    for (int k0 = 0; k0 < 768; k0 += 64) {
        __syncthreads();
#pragma unroll
        for (int r = 0; r < 2; ++r) {
            const int idx = tid + 256 * r;     // 0..511: A 64 rows x 8 chunks
            const int row = idx >> 3, cL = idx & 7, cD = cL ^ (row & 7);
            __builtin_amdgcn_global_load_lds(
                (__attribute__((address_space(1))) void*)(A + (size_t)(m0 + row) * 768 + k0 + cD * 8),
                (__attribute__((address_space(3))) void*)&As[idx * 8], 16, 0, 0);
        }
#pragma unroll
        for (int r = 0; r < 4; ++r) {
            const int idx = tid + 256 * r;     // 0..1023: W 128 rows x 8 chunks
            const int row = idx >> 3, cL = idx & 7, cD = cL ^ (row & 7);
            __builtin_amdgcn_global_load_lds(
                (__attribute__((address_space(1))) void*)(W + (size_t)(n0 + row) * 768 + k0 + cD * 8),
                (__attribute__((address_space(3))) void*)&Ws[idx * 8], 16, 0, 0);
        }
        __syncthreads();

        bf16x8 a[4][2], b[2][2];
#pragma unroll
        for (int mi = 0; mi < 4; ++mi)
#pragma unroll
            for (int kc = 0; kc < 2; ++kc)
                a[mi][kc] = lds8(As, mi * 16 + l16, kc * 4 + quad);
#pragma unroll
        for (int ni = 0; ni < 2; ++ni)
#pragma unroll
            for (int kc = 0; kc < 2; ++kc)
                b[ni][kc] = lds8(Ws, wv_ * 32 + ni * 16 + l16, kc * 4 + quad);
#pragma unroll
        for (int mi = 0; mi < 4; ++mi)
#pragma unroll
            for (int ni = 0; ni < 2; ++ni)
#pragma unroll
                for (int kc = 0; kc < 2; ++kc)
                    acc[mi][ni] = __builtin_amdgcn_mfma_f32_16x16x32_bf16(
                        a[mi][kc], b[ni][kc], acc[mi][ni], 0, 0, 0);
    }

#pragma unroll
    for (int ni = 0; ni < 2; ++ni) {
        const int n = n0 + wv_ * 32 + ni * 16 + l16;
        const float bn = bias[n];
#pragma unroll
        for (int mi = 0; mi < 4; ++mi) {
            const int mbase = m0 + mi * 16 + quad * 4;
            if (z == 2) {
                const int bb = mbase / S_, s = mbase - bb * S_;
                const int h = n >> 6, hd = n & 63;
                ushort4 o;
                o.x = f2bf(acc[mi][ni][0] + bn);
                o.y = f2bf(acc[mi][ni][1] + bn);
                o.z = f2bf(acc[mi][ni][2] + bn);
                o.w = f2bf(acc[mi][ni][3] + bn);
                *(ushort4*)&C[(((size_t)(bb * H_ + h) << 6) + hd) * S_ + s] = o;
            } else if (z < 2) {
#pragma unroll
                for (int reg = 0; reg < 4; ++reg) {
                    const int m = mbase + reg;
                    const int bb = m / S_, s = m - bb * S_;
                    const int h = n >> 6, hd = n & 63;
                    C[(((size_t)(bb * H_ + h) * S_ + s) << 6) + hd] =
                        f2bf(acc[mi][ni][reg] + bn);
                }
            } else {
#pragma unroll
                for (int reg = 0; reg < 4; ++reg)
                    C[(size_t)(mbase + reg) * 768 + n] = f2bf(acc[mi][ni][reg] + bn);
            }
        }
    }
}

// ---------------------------------------------------------------------------
// Output projection: 64x128 tile, BK=64, grid = 288 (48 m-tiles x 6 n-tiles).
// ---------------------------------------------------------------------------
__global__ __launch_bounds__(256) void gemm_out(
    const unsigned short* __restrict__ A, const unsigned short* __restrict__ W,
    const float* __restrict__ bias, float* __restrict__ C)
{
    const int mt = blockIdx.x / 6, nt = blockIdx.x - mt * 6;
    const int m0 = mt * 64, n0 = nt * 128;

    __shared__ unsigned short As[64 * 64];
    __shared__ unsigned short Ws[128 * 64];

    const int tid  = threadIdx.x;
    const int lane = tid & 63;
    const int wv_  = tid >> 6;
    const int quad = lane >> 4, l16 = lane & 15;

    floatx4 acc[4][2];
#pragma unroll
    for (int i = 0; i < 4; ++i)
#pragma unroll
        for (int j = 0; j < 2; ++j) acc[i][j] = (floatx4){0.f, 0.f, 0.f, 0.f};

    for (int k0 = 0; k0 < 768; k0 += 64) {
        __syncthreads();
#pragma unroll
        for (int r = 0; r < 2; ++r) {
            const int idx = tid + 256 * r;
            const int row = idx >> 3, cL = idx & 7, cD = cL ^ (row & 7);
            __builtin_amdgcn_global_load_lds(
                (__attribute__((address_space(1))) void*)(A + (size_t)(m0 + row) * 768 + k0 + cD * 8),
                (__attribute__((address_space(3))) void*)&As[idx * 8], 16, 0, 0);
        }
#pragma unroll
        for (int r = 0; r < 4; ++r) {
            const int idx = tid + 256 * r;
            const int row = idx >> 3, cL = idx & 7, cD = cL ^ (row & 7);
            __builtin_amdgcn_global_load_lds(
                (__attribute__((address_space(1))) void*)(W + (size_t)(n0 + row) * 768 + k0 + cD * 8),
                (__attribute__((address_space(3))) void*)&Ws[idx * 8], 16, 0, 0);
        }
        __syncthreads();

        bf16x8 a[4][2], b[2][2];
#pragma unroll
        for (int mi = 0; mi < 4; ++mi)
#pragma unroll
            for (int kc = 0; kc < 2; ++kc)
                a[mi][kc] = lds8(As, mi * 16 + l16, kc * 4 + quad);
#pragma unroll
        for (int ni = 0; ni < 2; ++ni)
#pragma unroll
            for (int kc = 0; kc < 2; ++kc)
                b[ni][kc] = lds8(Ws, wv_ * 32 + ni * 16 + l16, kc * 4 + quad);
#pragma unroll
        for (int mi = 0; mi < 4; ++mi)
#pragma unroll
            for (int ni = 0; ni < 2; ++ni)
#pragma unroll
                for (int kc = 0; kc < 2; ++kc)
                    acc[mi][ni] = __builtin_amdgcn_mfma_f32_16x16x32_bf16(
                        a[mi][kc], b[ni][kc], acc[mi][ni], 0, 0, 0);
    }

#pragma unroll
    for (int ni = 0; ni < 2; ++ni) {
        const int n = n0 + wv_ * 32 + ni * 16 + l16;
        const float bn = bias[n];
#pragma unroll
        for (int mi = 0; mi < 4; ++mi)
#pragma unroll
            for (int reg = 0; reg < 4; ++reg) {
                const int m = m0 + mi * 16 + quad * 4 + reg;
                C[(size_t)m * 768 + n] = acc[mi][ni][reg] + bn;
            }
    }
}

// ---------------------------------------------------------------------------
// MFMA flash attention (R10 version — best measured, 68 µs). LDS-staged
// K/Vt/PK/PQ via global_load_lds, single barrier, CP fp32 RMW (unique writer
// per cell), zero further syncs. LDS 65 KB -> 2 blocks/CU.
// grid = (6 it, 12 h, 48 = b*6+jt); 256 thr = 4 waves.
// ---------------------------------------------------------------------------
__global__ __launch_bounds__(256) void attn_mfma(
    const unsigned short* __restrict__ qg, const unsigned short* __restrict__ kg,
    const unsigned short* __restrict__ vtg,
    const unsigned short* __restrict__ pkg, const unsigned short* __restrict__ pqg,
    const int* __restrict__ seg, const float* __restrict__ sep,
    const int* __restrict__ mask,
    const float* __restrict__ same_bias, const float* __restrict__ cross_bias,
    const float* __restrict__ sep_scale, const float* __restrict__ sep_decay,
    unsigned short* __restrict__ part_O, float* __restrict__ part_ml)
{
    __shared__ unsigned short Ks [64 * 64];    //  8 KB  [j][d]   swizzled chunks
    __shared__ unsigned short Vts[64 * 64];    //  8 KB  [d][j]
    __shared__ unsigned short PKs[128 * 64];   // 16 KB  [ddloc][d]
    __shared__ unsigned short PQs[128 * 64];   // 16 KB
    __shared__ float CP[64 * 68];              // 17 KB score tile; Pp aliased

    const int tid  = threadIdx.x;
    const int lane = tid & 63, w = tid >> 6;
    const int l16  = lane & 15, quad = lane >> 4;
    const int ty = tid >> 4, tx = tid & 15;
    const int it = blockIdx.x, h = blockIdx.y;
    const int b  = blockIdx.z / 6, jt = blockIdx.z - 6 * b;
    const int i0 = it * 64, j0 = jt * 64;
    const size_t bh = (size_t)(b * H_ + h);

    const unsigned short* kbase  = kg  + bh * S_ * 64;
    const unsigned short* vtbase = vtg + bh * 64 * S_;
    const int dbase = i0 - j0 + 320;           // pk/pq window base (0..640)

    // ---- Q fragments from global (2 gathers, in flight with staging) ----
    bf16x8 qf[2];
#pragma unroll
    for (int ks = 0; ks < 2; ++ks)
        qf[ks] = gld8(qg + (bh * S_ + i0 + 16 * w + l16) * 64 + ks * 32 + quad * 8);

    // ---- stage K + Vt (64 rows x 8 chunks each) ----
#pragma unroll
    for (int r = 0; r < 2; ++r) {
        const int idx = tid + 256 * r;              // 0..511
        const int row = idx >> 3, cL = idx & 7;
        const int cD = cL ^ (row & 7);
        __builtin_amdgcn_global_load_lds(
            (__attribute__((address_space(1))) void*)(kbase + (size_t)(j0 + row) * 64 + cD * 8),
            (__attribute__((address_space(3))) void*)&Ks[idx * 8], 16, 0, 0);
        __builtin_amdgcn_global_load_lds(
            (__attribute__((address_space(1))) void*)(vtbase + (size_t)row * S_ + j0 + cD * 8),
            (__attribute__((address_space(3))) void*)&Vts[idx * 8], 16, 0, 0);
    }
    // ---- stage PK + PQ (128 rows x 8 chunks each) ----
#pragma unroll
    for (int r = 0; r < 4; ++r) {
        const int idx = tid + 256 * r;              // 0..1023
        const int row = idx >> 3, cL = idx & 7;
        const int cD = cL ^ (row & 7);
        const size_t go = (size_t)(dbase + row) * 768 + h * 64 + cD * 8;
        __builtin_amdgcn_global_load_lds(
            (__attribute__((address_space(1))) void*)(pkg + go),
            (__attribute__((address_space(3))) void*)&PKs[idx * 8], 16, 0, 0);
        __builtin_amdgcn_global_load_lds(
            (__attribute__((address_space(1))) void*)(pqg + go),
            (__attribute__((address_space(3))) void*)&PQs[idx * 8], 16, 0, 0);
    }

    // i-side metadata (independent loads, also in flight)
    float ai_r[4]; int si_r[4];
#pragma unroll
    for (int p = 0; p < 4; ++p) {
        const int ii = 4 * ty + p;
        ai_r[p] = fabsf(sep[b * S_ + i0 + ii]);
        si_r[p] = seg[b * S_ + i0 + ii];
    }

    const float sb  = same_bias[h];
    const float cb  = cross_bias[h];
    const float ssc = sep_scale[h];
    const float sd  = sep_decay[h];
    const float dec = fmaxf(sd, 0.f) + log1pf(__expf(-fabsf(sd))) + 1e-4f;
    const float isc = 0.07216878364870323f;    // 1/sqrt(64*3)

    __syncthreads();   // the ONE barrier: staging complete

    // ---- K fragments from LDS (kept in regs; used by c2c and p2c) ----
    bf16x8 kf[4][2];
#pragma unroll
    for (int nj = 0; nj < 4; ++nj)
#pragma unroll
        for (int ks = 0; ks < 2; ++ks)
            kf[nj][ks] = lds8(Ks, 16 * nj + l16, ks * 4 + quad);

    // ---- c2c: CP rows strip w = q . k ----
#pragma unroll
    for (int nj = 0; nj < 4; ++nj) {
        floatx4 acc = (floatx4){0.f, 0.f, 0.f, 0.f};
#pragma unroll
        for (int ks = 0; ks < 2; ++ks)
            acc = __builtin_amdgcn_mfma_f32_16x16x32_bf16(qf[ks], kf[nj][ks], acc, 0, 0, 0);
#pragma unroll
        for (int reg = 0; reg < 4; ++reg) {
            const int ii = 16 * w + quad * 4 + reg;
            CP[ii * 68 + 16 * nj + l16] = acc[reg];
        }
    }

    // ---- c2p (rows strip w): frags nd = w..w+4, scatter jj = ii-ddloc+63 ----
#pragma unroll
    for (int f = 0; f < 5; ++f) {
        const int nd = w + f;
        floatx4 acc = (floatx4){0.f, 0.f, 0.f, 0.f};
#pragma unroll
        for (int ks = 0; ks < 2; ++ks) {
            bf16x8 bf = lds8(PKs, 16 * nd + l16, ks * 4 + quad);
            acc = __builtin_amdgcn_mfma_f32_16x16x32_bf16(qf[ks], bf, acc, 0, 0, 0);
        }
        const int ddloc = 16 * nd + l16;
#pragma unroll
        for (int reg = 0; reg < 4; ++reg) {
            const int ii = 16 * w + quad * 4 + reg;
            const int jj = ii - ddloc + 63;
            if (jj >= 0 && jj < 64)
                CP[ii * 68 + jj] += acc[reg];      // unique writer per cell
        }
    }

    // ---- p2c (rows strip w): A=PQ (m=ddloc), B=K (n=jj);
    //      frags with nd+nj in {w+3, w+4}; guard ii in strip w ----
#pragma unroll
    for (int f = 0; f < 5; ++f) {
        const int nd = w + f;
        bf16x8 pqf[2];
#pragma unroll
        for (int ks = 0; ks < 2; ++ks)
            pqf[ks] = lds8(PQs, 16 * nd + l16, ks * 4 + quad);
#pragma unroll
        for (int g = 0; g < 2; ++g) {
            const int nj = (g == 0) ? (3 - f) : (4 - f);
            if (nj < 0 || nj > 3) continue;
            floatx4 acc = (floatx4){0.f, 0.f, 0.f, 0.f};
#pragma unroll
            for (int ks = 0; ks < 2; ++ks)
                acc = __builtin_amdgcn_mfma_f32_16x16x32_bf16(pqf[ks], kf[nj][ks], acc, 0, 0, 0);
            const int jj = 16 * nj + l16;
#pragma unroll
            for (int reg = 0; reg < 4; ++reg) {
                const int ddloc = 16 * nd + quad * 4 + reg;
                const int ii = ddloc + jj - 63;
                if (ii >= 16 * w && ii < 16 * w + 16)
                    CP[ii * 68 + jj] += acc[reg];  // unique writer per cell
            }
        }
    }

    // ---- softmax (rows strip w); P written bf16 into CP's buffer ----
    unsigned short* Pp = (unsigned short*)CP;      // pitch 136 shorts (272B)
    float* pml = part_ml + (size_t)(jt * 576 + ((b * H_ + h) * 6 + it)) * 128;
#pragma unroll
    for (int p = 0; p < 4; ++p) {
        const int ii = 4 * ty + p;
        const float aii = ai_r[p];
        const int   sii = si_r[p];
        float lg[4];
        float tmax = -INFINITY;
#pragma unroll
        for (int r = 0; r < 4; ++r) {
            const int jl = 4 * tx + r;
            float xv = CP[ii * 68 + jl] * isc;
            const float ajv = fabsf(sep[b * S_ + j0 + jl]);
            const int   sjv = seg[b * S_ + j0 + jl];
            const float gap = fabsf(aii - ajv);
            const float bias = (sii == sjv) ? sb
                             : cb + __expf(-gap * dec) * ssc;
            xv += bias;
            if (mask[b * S_ + j0 + jl] == 0) xv = -9.0e15f;
            lg[r] = xv;
            tmax = fmaxf(tmax, xv);
        }
#pragma unroll
        for (int off = 1; off < 16; off <<= 1)
            tmax = fmaxf(tmax, __shfl_xor(tmax, off));
        float rs = 0.f;
        ushort4 pw;
#pragma unroll
        for (int r = 0; r < 4; ++r) {
            const float e = __expf(lg[r] - tmax);
            rs += e;
            ((unsigned short*)&pw)[r] = f2bf(e);
        }
#pragma unroll
        for (int off = 1; off < 16; off <<= 1)
            rs += __shfl_xor(rs, off);
        if (tx == 0) {
            pml[ii]      = tmax;
            pml[64 + ii] = rs;
        }
        // write AFTER all this wave's reads of CP row ii (program order)
        *(ushort4*)&Pp[ii * 136 + 4 * tx] = pw;
    }

    // ---- PV (rows strip w): O = P x Vt ----
    bf16x8 pA[2];
#pragma unroll
    for (int ks = 0; ks < 2; ++ks)
        pA[ks] = __builtin_bit_cast(bf16x8,
            *(const ux4*)&Pp[(16 * w + l16) * 136 + ks * 32 + quad * 8]);
    floatx4 O[4];
#pragma unroll
    for (int nd = 0; nd < 4; ++nd) {
        O[nd] = (floatx4){0.f, 0.f, 0.f, 0.f};
#pragma unroll
        for (int ks = 0; ks < 2; ++ks) {
            bf16x8 bf = lds8(Vts, 16 * nd + l16, ks * 4 + quad);
            O[nd] = __builtin_amdgcn_mfma_f32_16x16x32_bf16(pA[ks], bf, O[nd], 0, 0, 0);
        }
    }

    // ---- epilogue: write unnormalized partial O ----
    unsigned short* pO = part_O + (size_t)(jt * 576 + ((b * H_ + h) * 6 + it)) * 4096;
#pragma unroll
    for (int nd = 0; nd < 4; ++nd) {
        const int d = 16 * nd + l16;
#pragma unroll
        for (int reg = 0; reg < 4; ++reg) {
            const int ii = 16 * w + quad * 4 + reg;
            pO[ii * 64 + d] = f2bf(O[nd][reg]);
        }
    }
}

// ---------------------------------------------------------------------------
// Merge the 6 split-j partials -> vals (bf16, (B,S,E)). grid=576, 256 thr.
// ---------------------------------------------------------------------------
__global__ __launch_bounds__(256) void merge_attn(
    const unsigned short* __restrict__ part_O, const float* __restrict__ part_ml,
    unsigned short* __restrict__ vals)
{
    const int idx = blockIdx.x;                 // ((b*H+h)*6+it)
    const int b  = idx / (H_ * 6);
    const int r  = idx - b * H_ * 6;
    const int h  = r / 6, it = r - h * 6;
    const int tid = threadIdx.x;
    const int ii = tid >> 2, c = (tid & 3) * 16;

    float m[6], l[6];
#pragma unroll
    for (int jc = 0; jc < 6; ++jc) {
        const float* pml = part_ml + (size_t)(jc * 576 + idx) * 128;
        m[jc] = pml[ii];
        l[jc] = pml[64 + ii];
    }
    float M = m[0];
#pragma unroll
    for (int jc = 1; jc < 6; ++jc) M = fmaxf(M, m[jc]);
    float wsum = 0.f, wc[6];
#pragma unroll
    for (int jc = 0; jc < 6; ++jc) {
        wc[jc] = __expf(m[jc] - M);
        wsum += wc[jc] * l[jc];
    }
    const float inv = (wsum > 0.f) ? 1.f / wsum : 0.f;

    float o[16];
#pragma unroll
    for (int e = 0; e < 16; ++e) o[e] = 0.f;
#pragma unroll
    for (int jc = 0; jc < 6; ++jc) {
        const unsigned short* pO = part_O + ((size_t)(jc * 576 + idx)) * 4096
                                 + ii * 64 + c;
        ux4 u0 = *(const ux4*)pO;
        ux4 u1 = *(const ux4*)(pO + 8);
        const unsigned short* us0 = (const unsigned short*)&u0;
        const unsigned short* us1 = (const unsigned short*)&u1;
#pragma unroll
        for (int e = 0; e < 8; ++e) {
            o[e]     += wc[jc] * bf2f(us0[e]);
            o[8 + e] += wc[jc] * bf2f(us1[e]);
        }
    }
    ushort4 w0, w1, w2, w3;
#pragma unroll
    for (int e = 0; e < 4; ++e) {
        ((unsigned short*)&w0)[e] = f2bf(o[e] * inv);
        ((unsigned short*)&w1)[e] = f2bf(o[4 + e] * inv);
        ((unsigned short*)&w2)[e] = f2bf(o[8 + e] * inv);
        ((unsigned short*)&w3)[e] = f2bf(o[12 + e] * inv);
    }
    unsigned short* dst = vals + ((size_t)(b * S_ + it * 64 + ii)) * E_ + h * 64 + c;
    *(ushort4*)(dst)      = w0;
    *(ushort4*)(dst + 4)  = w1;
    *(ushort4*)(dst + 8)  = w2;
    *(ushort4*)(dst + 12) = w3;
}

// ---------------------------------------------------------------------------
// Launcher. Workspace (shorts unless noted): xb 2359296; 7x589824 weights/rel;
// qb,kb,vtb 3x2359296; pkb,pqb 2x589824; valsb 2359296; part_O 6x576x4096;
// part_ml fp32 6x576x128. ~69 MiB.
// ---------------------------------------------------------------------------
extern "C" void kernel_launch(void* const* d_in, const int* in_sizes, int n_in,
                              void* d_out, int out_size, void* d_ws, size_t ws_size,
                              hipStream_t stream)
{
    const float* x         = (const float*)d_in[0];
    const int*   mask      = (const int*)d_in[1];
    const int*   seg       = (const int*)d_in[2];
    const float* sep       = (const float*)d_in[3];
    const float* Wq        = (const float*)d_in[4];
    const float* bq        = (const float*)d_in[5];
    const float* Wk        = (const float*)d_in[6];
    const float* bk        = (const float*)d_in[7];
    const float* Wv        = (const float*)d_in[8];
    const float* bv        = (const float*)d_in[9];
    const float* rel_emb   = (const float*)d_in[10];
    const float* Wpk       = (const float*)d_in[11];
    const float* bpk       = (const float*)d_in[12];
    const float* Wpq       = (const float*)d_in[13];
    const float* bpq       = (const float*)d_in[14];
    const float* same_bias = (const float*)d_in[15];
    const float* cross_bias= (const float*)d_in[16];
    const float* sep_scale = (const float*)d_in[17];
    const float* sep_decay = (const float*)d_in[18];
    const float* Wo        = (const float*)d_in[19];
    const float* bo        = (const float*)d_in[20];

    const size_t QKVN = (size_t)B_ * S_ * E_;   // 2359296
    const size_t WN   = (size_t)768 * 768;      //  589824

    unsigned short* xb    = (unsigned short*)d_ws;
    unsigned short* wqb   = xb   + QKVN;
    unsigned short* wkb   = wqb  + WN;
    unsigned short* wvb   = wkb  + WN;
    unsigned short* wob   = wvb  + WN;
    unsigned short* wpkb  = wob  + WN;
    unsigned short* wpqb  = wpkb + WN;
    unsigned short* relb  = wpqb + WN;
    unsigned short* qb    = relb + WN;
    unsigned short* kb    = qb   + QKVN;
    unsigned short* vtb   = kb   + QKVN;
    unsigned short* pkb   = vtb  + QKVN;
    unsigned short* pqb   = pkb  + WN;
    unsigned short* valsb = pqb  + WN;
    unsigned short* partO = valsb + QKVN;                       // 6*576*4096 shorts
    float*          partml= (float*)(partO + (size_t)6 * 576 * 4096);

    // 1) convert all operands to bf16
    convert_all<<<dim3(576, 11), 256, 0, stream>>>(
        x, Wq, Wk, Wv, Wo, Wpk, Wpq, rel_emb + (size_t)128 * D_,
        xb, wqb, wkb, wvb, wob, wpkb, wpqb, relb);

    // 2) fused Q/K/Vt/pk/pq projections (64x128 tiles, 1008 blocks)
    proj_all<<<dim3(1008), 256, 0, stream>>>(
        xb, relb, wqb, wkb, wvb, wpkb, wpqb,
        bq, bk, bv, bpk, bpq, qb, kb, vtb, pkb, pqb);

    // 3) MFMA flash attention (R10 version), split-j x6
    attn_mfma<<<dim3(6, 12, 48), 256, 0, stream>>>(
        qb, kb, vtb, pkb, pqb, seg, sep, mask,
        same_bias, cross_bias, sep_scale, sep_decay, partO, partml);

    // 4) merge partials -> valsb
    merge_attn<<<dim3(576), 256, 0, stream>>>(partO, partml, valsb);

    // 5) output projection (64x128 tiles, 288 blocks)
    gemm_out<<<dim3(288), 256, 0, stream>>>(valsb, wob, bo, (float*)d_out);
}